// Round 7
// baseline (189.730 us; speedup 1.0000x reference)
//
#include <hip/hip_runtime.h>
#include <math.h>

// GCN 2-layer, algebraically fused, ATOMIC-FREE (global):
//   agg_x[d] = dinv[d]*(sum_{s in N(d)} xp[s] + xp[d]),  xp = dinv*x
//   h = relu(agg_x@W1+b1); g = h@W2; gp = dinv*g
//   out = log_softmax(dinv[d]*(sum gp[s] + gp[d]) + b2)
//
// R2: bucketed counting sort (256 nodes/bucket) + per-bucket LDS aggregation.
// R3: parallel scan.  R4: 8-way sliced agg, premultiplied dinv, staged scatter.
// R5: stage_b[] (no binary search), shuffle scans, int4 edge loads.
// R6: (a) SoA LDS accumulators accx/accy — interleaved acc[2*dl] put every .x
//     atomic on an even bank (16/32 banks = 4-way conflict, 1.58x per m136);
//     SoA makes bank = dl%32, uniform over 32 -> ~free. partial buffer SoA too.
//     (b) deg/agg inner loops restructured to 4 independent guarded loads per
//     iteration (ILP-4 on the record->gather chain).

#define BLK 256
#define NTILE 512
#define EPTMAX 6400        // >= runtime ept (6252), multiple of 4
#define MAXB 512           // >= nbkt = 391
#define NS 8               // slices per bucket in Phase B

// ---------- Phase A ----------

// A1: per-tile bucket histogram -> table[tile*nbkt + b]
__global__ void k_hist(const int* __restrict__ dst, int* __restrict__ table,
                       int e, int ept, int nbkt) {
    __shared__ int h[MAXB];
    int tile = blockIdx.x;
    for (int i = threadIdx.x; i < MAXB; i += BLK) h[i] = 0;
    __syncthreads();
    int lo = tile * ept;
    int hi = min(lo + ept, e);
    for (int i = lo + 4 * threadIdx.x; i < hi; i += 4 * BLK) {
        int4 d4 = *(const int4*)(dst + i);
        atomicAdd(&h[d4.x >> 8], 1);
        atomicAdd(&h[d4.y >> 8], 1);
        atomicAdd(&h[d4.z >> 8], 1);
        atomicAdd(&h[d4.w >> 8], 1);
    }
    __syncthreads();
    for (int i = threadIdx.x; i < nbkt; i += BLK)
        table[tile * nbkt + i] = h[i];
}

// A2a: per-bucket column scan over NTILE tiles. Shuffle scan.
__global__ void k_scan_col(int* __restrict__ table, int* __restrict__ tot, int nbkt) {
    __shared__ int wsum[NTILE / 64];
    int b = blockIdx.x;
    int t = threadIdx.x;
    int v = table[t * nbkt + b];
    int x = v;
    int lane = t & 63;
#pragma unroll
    for (int ofs = 1; ofs < 64; ofs <<= 1) {
        int y = __shfl_up(x, ofs, 64);
        if (lane >= ofs) x += y;
    }
    if (lane == 63) wsum[t >> 6] = x;
    __syncthreads();
    if (t < NTILE / 64) {
        int s = wsum[t];
        int w = s;
#pragma unroll
        for (int ofs = 1; ofs < NTILE / 64; ofs <<= 1) {
            int y = __shfl_up(w, ofs, 64);
            if (t >= ofs) w += y;
        }
        wsum[t] = w - s;
    }
    __syncthreads();
    int incl = x + wsum[t >> 6];
    table[t * nbkt + b] = incl - v;
    if (t == NTILE - 1) tot[b] = incl;
}

// A2b: exclusive scan of bucket totals -> bkt_off (+ sentinel). Shuffle scan.
__global__ void k_scan_tot(const int* __restrict__ tot, int* __restrict__ bkt_off, int nbkt) {
    __shared__ int wsum[MAXB / 64];
    int t = threadIdx.x;               // MAXB threads
    int v = (t < nbkt) ? tot[t] : 0;
    int x = v;
    int lane = t & 63;
#pragma unroll
    for (int ofs = 1; ofs < 64; ofs <<= 1) {
        int y = __shfl_up(x, ofs, 64);
        if (lane >= ofs) x += y;
    }
    if (lane == 63) wsum[t >> 6] = x;
    __syncthreads();
    if (t < MAXB / 64) {
        int s = wsum[t];
        int w = s;
#pragma unroll
        for (int ofs = 1; ofs < MAXB / 64; ofs <<= 1) {
            int y = __shfl_up(w, ofs, 64);
            if (t >= ofs) w += y;
        }
        wsum[t] = w - s;
    }
    __syncthreads();
    int incl = x + wsum[t >> 6];
    if (t < nbkt) bkt_off[t] = incl - v;
    if (t == nbkt - 1) bkt_off[nbkt] = incl;
}

// A3: staged scatter. Local counting sort in LDS, bucket-contiguous writes.
__global__ void k_scatter(const int* __restrict__ src, const int* __restrict__ dst,
                          const int* __restrict__ table, const int* __restrict__ tot,
                          const int* __restrict__ bkt_off, unsigned* __restrict__ sorted,
                          int e, int ept, int nbkt) {
    __shared__ int cur[MAXB];
    __shared__ int base2[MAXB];
    __shared__ unsigned stage[EPTMAX];
    __shared__ unsigned short stage_b[EPTMAX];
    __shared__ int wpart[BLK / 64];
    int tile = blockIdx.x;
    int t = threadIdx.x;
    int lo = tile * ept;
    int hi = min(lo + ept, e);
    int total = hi - lo;

    int b0 = 2 * t, b1 = 2 * t + 1;
    int c0 = 0, c1 = 0, g0 = 0, g1 = 0;
    if (b0 < nbkt) {
        int base = table[tile * nbkt + b0];
        int next = (tile < NTILE - 1) ? table[(tile + 1) * nbkt + b0] : tot[b0];
        c0 = next - base;
        g0 = bkt_off[b0] + base;
    }
    if (b1 < nbkt) {
        int base = table[tile * nbkt + b1];
        int next = (tile < NTILE - 1) ? table[(tile + 1) * nbkt + b1] : tot[b1];
        c1 = next - base;
        g1 = bkt_off[b1] + base;
    }
    int p = c0 + c1;
    int x = p;
    int lane = t & 63;
#pragma unroll
    for (int ofs = 1; ofs < 64; ofs <<= 1) {
        int y = __shfl_up(x, ofs, 64);
        if (lane >= ofs) x += y;
    }
    if (lane == 63) wpart[t >> 6] = x;
    __syncthreads();
    if (t < BLK / 64) {
        int s = wpart[t];
        int w = s;
#pragma unroll
        for (int ofs = 1; ofs < BLK / 64; ofs <<= 1) {
            int y = __shfl_up(w, ofs, 64);
            if (t >= ofs) w += y;
        }
        wpart[t] = w - s;
    }
    __syncthreads();
    int E = x + wpart[t >> 6] - p;
    cur[b0] = E;
    cur[b1] = E + c0;
    if (b0 < nbkt) base2[b0] = g0 - E;
    if (b1 < nbkt) base2[b1] = g1 - (E + c0);
    __syncthreads();

    for (int i = lo + 4 * t; i < hi; i += 4 * BLK) {
        int4 s4 = *(const int4*)(src + i);
        int4 d4 = *(const int4*)(dst + i);
        int b, pos;
        b = d4.x >> 8; pos = atomicAdd(&cur[b], 1);
        stage[pos] = (unsigned)s4.x | ((unsigned)(d4.x & 255) << 17); stage_b[pos] = (unsigned short)b;
        b = d4.y >> 8; pos = atomicAdd(&cur[b], 1);
        stage[pos] = (unsigned)s4.y | ((unsigned)(d4.y & 255) << 17); stage_b[pos] = (unsigned short)b;
        b = d4.z >> 8; pos = atomicAdd(&cur[b], 1);
        stage[pos] = (unsigned)s4.z | ((unsigned)(d4.z & 255) << 17); stage_b[pos] = (unsigned short)b;
        b = d4.w >> 8; pos = atomicAdd(&cur[b], 1);
        stage[pos] = (unsigned)s4.w | ((unsigned)(d4.w & 255) << 17); stage_b[pos] = (unsigned short)b;
    }
    __syncthreads();
    for (int j = t; j < total; j += BLK) {
        int b = stage_b[j];
        sorted[base2[b] + j] = stage[j];
    }
}

// ---------- degree ----------

__global__ void k_deg_slice(const unsigned* __restrict__ sorted, const int* __restrict__ bkt_off,
                            int* __restrict__ pdeg) {
    __shared__ int cnt[256];
    int b = blockIdx.x, s = blockIdx.y;
    cnt[threadIdx.x] = 0;
    __syncthreads();
    int lo = bkt_off[b], hi = bkt_off[b + 1];
    int len = hi - lo;
    int slo = lo + (int)((long long)len * s / NS);
    int shi = lo + (int)((long long)len * (s + 1) / NS);
    for (int i = slo + threadIdx.x; i < shi; i += 4 * BLK) {
        int i1 = i + BLK, i2 = i + 2 * BLK, i3 = i + 3 * BLK;
        unsigned p0 = sorted[i];
        unsigned p1 = (i1 < shi) ? sorted[i1] : 0;
        unsigned p2 = (i2 < shi) ? sorted[i2] : 0;
        unsigned p3 = (i3 < shi) ? sorted[i3] : 0;
        atomicAdd(&cnt[p0 >> 17], 1);
        if (i1 < shi) atomicAdd(&cnt[p1 >> 17], 1);
        if (i2 < shi) atomicAdd(&cnt[p2 >> 17], 1);
        if (i3 < shi) atomicAdd(&cnt[p3 >> 17], 1);
    }
    __syncthreads();
    pdeg[(b * NS + s) * 256 + threadIdx.x] = cnt[threadIdx.x];
}

__global__ void k_dinv_merge(const int* __restrict__ pdeg, const float* __restrict__ x,
                             float* __restrict__ dinv, float* __restrict__ xp, int n) {
    int i = blockIdx.x * BLK + threadIdx.x;
    if (i >= n) return;
    int b = i >> 8, t = i & 255;
    int deg = 1;  // self loop
#pragma unroll
    for (int s = 0; s < NS; ++s) deg += pdeg[(b * NS + s) * 256 + t];
    float d = rsqrtf((float)deg);
    dinv[i] = d;
    float2 xv = ((const float2*)x)[i];
    ((float2*)xp)[i] = make_float2(d * xv.x, d * xv.y);
}

// ---------- Phase B: sliced aggregation, SoA accumulators ----------

__global__ void k_agg_slice(const unsigned* __restrict__ sorted, const int* __restrict__ bkt_off,
                            const float* __restrict__ featp, float* __restrict__ partial) {
    __shared__ float accx[256];
    __shared__ float accy[256];
    int b = blockIdx.x, s = blockIdx.y;
    accx[threadIdx.x] = 0.f;
    accy[threadIdx.x] = 0.f;
    __syncthreads();
    int lo = bkt_off[b], hi = bkt_off[b + 1];
    int len = hi - lo;
    int slo = lo + (int)((long long)len * s / NS);
    int shi = lo + (int)((long long)len * (s + 1) / NS);
    for (int i = slo + threadIdx.x; i < shi; i += 4 * BLK) {
        int i1 = i + BLK, i2 = i + 2 * BLK, i3 = i + 3 * BLK;
        unsigned p0 = sorted[i];
        unsigned p1 = (i1 < shi) ? sorted[i1] : 0;
        unsigned p2 = (i2 < shi) ? sorted[i2] : 0;
        unsigned p3 = (i3 < shi) ? sorted[i3] : 0;
        float2 f0 = ((const float2*)featp)[p0 & 0x1FFFFu];
        float2 f1 = ((const float2*)featp)[p1 & 0x1FFFFu];
        float2 f2 = ((const float2*)featp)[p2 & 0x1FFFFu];
        float2 f3 = ((const float2*)featp)[p3 & 0x1FFFFu];
        atomicAdd(&accx[p0 >> 17], f0.x);
        atomicAdd(&accy[p0 >> 17], f0.y);
        if (i1 < shi) { atomicAdd(&accx[p1 >> 17], f1.x); atomicAdd(&accy[p1 >> 17], f1.y); }
        if (i2 < shi) { atomicAdd(&accx[p2 >> 17], f2.x); atomicAdd(&accy[p2 >> 17], f2.y); }
        if (i3 < shi) { atomicAdd(&accx[p3 >> 17], f3.x); atomicAdd(&accy[p3 >> 17], f3.y); }
    }
    __syncthreads();
    float* P = &partial[(size_t)(b * NS + s) * 512];
    P[threadIdx.x]       = accx[threadIdx.x];
    P[256 + threadIdx.x] = accy[threadIdx.x];
}

__global__ void k_mlp_merge(const float* __restrict__ partial, const float* __restrict__ dinv,
                            const float* __restrict__ xp,
                            const float* __restrict__ W1, const float* __restrict__ b1,
                            const float* __restrict__ W2, float* __restrict__ gp, int n) {
    int i = blockIdx.x * BLK + threadIdx.x;
    if (i >= n) return;
    int b = i >> 8, t = i & 255;
    float2 xv = ((const float2*)xp)[i];
    float ax = xv.x, ay = xv.y;
#pragma unroll
    for (int s = 0; s < NS; ++s) {
        const float* P = &partial[(size_t)(b * NS + s) * 512];
        ax += P[t]; ay += P[256 + t];
    }
    float d = dinv[i];
    ax *= d; ay *= d;
    float g0 = 0.f, g1 = 0.f;
#pragma unroll
    for (int f = 0; f < 16; ++f) {
        float h = fmaf(ax, W1[f], fmaf(ay, W1[16 + f], b1[f]));
        h = fmaxf(h, 0.0f);
        g0 = fmaf(h, W2[2 * f + 0], g0);
        g1 = fmaf(h, W2[2 * f + 1], g1);
    }
    ((float2*)gp)[i] = make_float2(d * g0, d * g1);
}

__global__ void k_final(const float* __restrict__ partial, const float* __restrict__ dinv,
                        const float* __restrict__ gp, const float* __restrict__ b2,
                        float* __restrict__ out, int n) {
    int i = blockIdx.x * BLK + threadIdx.x;
    if (i >= n) return;
    int b = i >> 8, t = i & 255;
    float2 gv = ((const float2*)gp)[i];
    float ax = gv.x, ay = gv.y;
#pragma unroll
    for (int s = 0; s < NS; ++s) {
        const float* P = &partial[(size_t)(b * NS + s) * 512];
        ax += P[t]; ay += P[256 + t];
    }
    float d = dinv[i];
    float z0 = d * ax + b2[0];
    float z1 = d * ay + b2[1];
    float m = fmaxf(z0, z1);
    float lse = m + logf(expf(z0 - m) + expf(z1 - m));
    ((float2*)out)[i] = make_float2(z0 - lse, z1 - lse);
}

extern "C" void kernel_launch(void* const* d_in, const int* in_sizes, int n_in,
                              void* d_out, int out_size, void* d_ws, size_t ws_size,
                              hipStream_t stream) {
    const float* x  = (const float*)d_in[0];   // [n,2]
    const int*   ei = (const int*)d_in[1];     // [2,e]: row0=src, row1=dst
    const float* W1 = (const float*)d_in[2];   // [2,16]
    const float* b1 = (const float*)d_in[3];   // [16]
    const float* W2 = (const float*)d_in[4];   // [16,2]
    const float* b2 = (const float*)d_in[5];   // [2]
    float* out = (float*)d_out;                // [n,2]

    const int n = in_sizes[0] / 2;             // 100000
    const int e = in_sizes[1] / 2;             // 3200000
    const int* src = ei;
    const int* dst = ei + e;

    const int nbkt = (n + 255) >> 8;           // 391
    int ept = (((e + NTILE - 1) / NTILE) + 3) & ~3;   // 6252

    char* base = (char*)d_ws;
    size_t off = 0;
    auto take = [&](size_t bytes) { char* p = base + off; off += (bytes + 255) & ~(size_t)255; return p; };
    unsigned* sorted  = (unsigned*)take((size_t)e * 4);                   // 12.8 MB
    int*      table   = (int*)take((size_t)NTILE * nbkt * 4);             // 0.8 MB
    int*      tot     = (int*)take((size_t)MAXB * 4);
    int*      bkt_off = (int*)take((size_t)(MAXB + 1) * 4);
    float*    partial = (float*)take((size_t)nbkt * NS * 512 * 4);        // 6.4 MB (also pdeg)
    int*      pdeg    = (int*)partial;
    float*    dinv    = (float*)take((size_t)n * 4);
    float*    xp      = (float*)take((size_t)n * 8);
    float*    gp      = (float*)take((size_t)n * 8);

    const int gn = (n + BLK - 1) / BLK;
    dim3 gslice(nbkt, NS);

    k_hist      <<<NTILE, BLK, 0, stream>>>(dst, table, e, ept, nbkt);
    k_scan_col  <<<nbkt, NTILE, 0, stream>>>(table, tot, nbkt);
    k_scan_tot  <<<1, MAXB, 0, stream>>>(tot, bkt_off, nbkt);
    k_scatter   <<<NTILE, BLK, 0, stream>>>(src, dst, table, tot, bkt_off, sorted, e, ept, nbkt);
    k_deg_slice <<<gslice, BLK, 0, stream>>>(sorted, bkt_off, pdeg);
    k_dinv_merge<<<gn, BLK, 0, stream>>>(pdeg, x, dinv, xp, n);
    k_agg_slice <<<gslice, BLK, 0, stream>>>(sorted, bkt_off, xp, partial);   // layer 1
    k_mlp_merge <<<gn, BLK, 0, stream>>>(partial, dinv, xp, W1, b1, W2, gp, n);
    k_agg_slice <<<gslice, BLK, 0, stream>>>(sorted, bkt_off, gp, partial);   // layer 2
    k_final     <<<gn, BLK, 0, stream>>>(partial, dinv, gp, b2, out, n);
}